// Round 5
// baseline (175.646 us; speedup 1.0000x reference)
//
#include <hip/hip_runtime.h>
#include <hip/hip_bf16.h>
#include <math.h>

// Shapes
#define Bn 256
#define Tn 64
#define Kn 49
#define Hn 512
#define An 49

// Workspace layout (floats):
//   Ev = e^{2*cv} : Bn*Kn*An = 614656   @ 0
//   Eg = e^{2*cg} : Bn*Tn*An = 802816   @ 614656
//   Es = e^{2*cs} : Bn*Tn*An = 802816   @ 1417472
//   Wf = bf16 swizzled W fragments (3*4096 short8 = 196608 B) @ 2220288
#define WS_EV 0
#define WS_EG 614656
#define WS_ES 1417472
#define WS_WF 2220288

// Output layout (floats):
//   c_hat : Bn*Tn*Hn = 8388608 @ 0
//   alpha : Bn*Tn*Kn = 802816  @ 8388608
//   beta  : Bn*Tn    = 16384   @ 9191424
#define OUT_ALPHA 8388608
#define OUT_BETA  9191424

typedef __attribute__((ext_vector_type(8))) short short8;
typedef __attribute__((ext_vector_type(4))) float f32x4;

__device__ __forceinline__ short bfc(float x) {
    __hip_bfloat16 h = __float2bfloat16(x);
    return __builtin_bit_cast(short, h);
}

// ---------------------------------------------------------------------------
// prep_w: convert W{v,g,s} (49x512 fp32) into bf16 MFMA B-fragment order:
//   frag index = part*4096 + (ct*16 + ks)*64 + lane, holding 8 bf16:
//   row = ct*16 + (lane&15), k = (lane>>4)*8 + ks*32 + j.  rows>=49 -> 0.
// 12288 threads total.
// ---------------------------------------------------------------------------
__global__ __launch_bounds__(256) void prep_w(
    const float* __restrict__ Wv, const float* __restrict__ Wg,
    const float* __restrict__ Ws, float* __restrict__ ws)
{
    const int tid = blockIdx.x * 256 + threadIdx.x;   // 0..12287
    const int part = tid >> 12;
    const int rem  = tid & 4095;
    const int lane = rem & 63;
    const int ks   = (rem >> 6) & 15;
    const int ct   = rem >> 10;
    const int row  = ct * 16 + (lane & 15);
    const int k0   = (lane >> 4) * 8 + ks * 32;
    const float* W = (part == 0) ? Wv : (part == 1) ? Wg : Ws;

    short8 s;
    #pragma unroll
    for (int j = 0; j < 8; ++j) s[j] = 0;
    if (row < Kn) {
        float4 v0 = *(const float4*)(W + (size_t)row * Hn + k0);
        float4 v1 = *(const float4*)(W + (size_t)row * Hn + k0 + 4);
        s[0] = bfc(v0.x); s[1] = bfc(v0.y); s[2] = bfc(v0.z); s[3] = bfc(v0.w);
        s[4] = bfc(v1.x); s[5] = bfc(v1.y); s[6] = bfc(v1.z); s[7] = bfc(v1.w);
    }
    ((short8*)((short*)(ws + WS_WF)))[tid] = s;
}

// ---------------------------------------------------------------------------
// Kernel 1: three per-batch GEMMs vs H=512 via bf16 MFMA, LDS-free.
// B-fragments come pre-swizzled from ws (L2-hot, coalesced 1KB/instr).
// Epilogue stores e^{2*acc}  (tanh(x) = 1 - 2/(e^{2x}+1) consumed in fused).
//   part 0: Ev[b][k][a], R=49   part 1: Eg[b][t][a], R=64   part 2: Es, R=64
// 4 waves/block: wave = 16-row tile; 4 col-tiles x 16 K-steps.
// ---------------------------------------------------------------------------
__global__ __launch_bounds__(256) void gemm3_mfma(
    const float* __restrict__ V, const float* __restrict__ h_t,
    const float* __restrict__ s_t, float* __restrict__ ws)
{
    const int b = blockIdx.x;
    const int part = blockIdx.y;

    const float* A;
    float* out;
    int R;
    if (part == 0)      { A = V   + (size_t)b*Kn*Hn; out = ws + WS_EV + (size_t)b*Kn*An; R = Kn; }
    else if (part == 1) { A = h_t + (size_t)b*Tn*Hn; out = ws + WS_EG + (size_t)b*Tn*An; R = Tn; }
    else                { A = s_t + (size_t)b*Tn*Hn; out = ws + WS_ES + (size_t)b*Tn*An; R = Tn; }

    const short8* wf = (const short8*)((const short*)(ws + WS_WF)) + (size_t)part * 4096;

    const int tid  = threadIdx.x;
    const int wave = tid >> 6;
    const int lane = tid & 63;
    const int l15  = lane & 15;
    const int kgrp = lane >> 4;        // 0..3
    const int koff = kgrp * 8;

    const int r0 = wave * 16;
    int arow = r0 + l15; if (arow >= R) arow = R - 1;   // clamp (masked at write)
    const float* Ap = A + (size_t)arow * Hn + koff;

    f32x4 acc[4] = {{0,0,0,0},{0,0,0,0},{0,0,0,0},{0,0,0,0}};

    #pragma unroll 4
    for (int ks = 0; ks < 16; ++ks) {
        float4 a0 = *(const float4*)(Ap + ks * 32);
        float4 a1 = *(const float4*)(Ap + ks * 32 + 4);
        short8 af;
        af[0] = bfc(a0.x); af[1] = bfc(a0.y); af[2] = bfc(a0.z); af[3] = bfc(a0.w);
        af[4] = bfc(a1.x); af[5] = bfc(a1.y); af[6] = bfc(a1.z); af[7] = bfc(a1.w);
        const short8* wp = wf + ks * 64 + lane;
        acc[0] = __builtin_amdgcn_mfma_f32_16x16x32_bf16(af, wp[0],       acc[0], 0, 0, 0);
        acc[1] = __builtin_amdgcn_mfma_f32_16x16x32_bf16(af, wp[16 * 64], acc[1], 0, 0, 0);
        acc[2] = __builtin_amdgcn_mfma_f32_16x16x32_bf16(af, wp[32 * 64], acc[2], 0, 0, 0);
        acc[3] = __builtin_amdgcn_mfma_f32_16x16x32_bf16(af, wp[48 * 64], acc[3], 0, 0, 0);
    }

    #pragma unroll
    for (int ct = 0; ct < 4; ++ct) {
        const int a = ct * 16 + l15;
        if (a >= An) continue;
        #pragma unroll
        for (int i = 0; i < 4; ++i) {
            const int k = r0 + kgrp * 4 + i;
            if (k < R) out[(size_t)k * An + a] = __expf(2.0f * acc[ct][i]);
        }
    }
}

// ---------------------------------------------------------------------------
// Kernel 2: fused score + softmax + c_t + c_hat per (b, 16-row t-tile).
// grid = 1024 blocks (256 b * 4 tiles), 256 threads (4 waves).
//   z[t][k]  = Swh - 2 * sum_a wh[a] / (Eg[t][a]*Ev[k][a] + 1)
//   z_ext[t] = Swh - 2 * sum_a wh[a] / (Eg[t][a]*Es[t][a] + 1)
// c_t phase: thread owns float2 h-slice for all 16 rows (coalesced V reads,
// panel read once per block).
// ---------------------------------------------------------------------------
#define TT 16
#define AP 52   // padded A stride (multiple of 4; pads: wh=0, E*=1)

__global__ __launch_bounds__(256) void fused_kernel(
    const float* __restrict__ V, const float* __restrict__ s_t,
    const float* __restrict__ Wh, const float* __restrict__ ws,
    float* __restrict__ out)
{
    const int bid = blockIdx.x;
    const int b  = bid >> 2;
    const int t0 = (bid & 3) * TT;

    __shared__ float EvL[Kn * AP];     // 10.2 KB
    __shared__ float EgL[TT * AP];     // 3.3 KB
    __shared__ float EcL[TT * AP];     // 3.3 KB  (= Eg*Es)
    __shared__ float whL[AP];
    __shared__ float zl[TT][Kn + 1];
    __shared__ float al[TT][AP];       // alpha, pads zeroed
    __shared__ float bl[TT];
    __shared__ float swhL;

    const int tid = threadIdx.x;

    // ---- stage ----
    {
        const float* evg = ws + WS_EV + (size_t)b * Kn * An;
        for (int i = tid; i < Kn * An; i += 256) {
            const int r = i / An;
            const int c = i - r * An;
            EvL[r * AP + c] = evg[i];
        }
        const float* egg = ws + WS_EG + ((size_t)b * Tn + t0) * An;
        const float* esg = ws + WS_ES + ((size_t)b * Tn + t0) * An;
        for (int i = tid; i < TT * An; i += 256) {
            const int r = i / An;
            const int c = i - r * An;
            const float eg = egg[i];
            EgL[r * AP + c] = eg;
            EcL[r * AP + c] = eg * esg[i];
        }
        // pads (must be finite: product enters rcp; wh pad=0 kills contribution)
        if (tid < Kn * 3) {
            const int r = tid / 3;
            const int c = An + (tid - r * 3);
            EvL[r * AP + c] = 1.f;
        }
        if (tid >= 64 && tid < 64 + TT * 3) {
            const int j = tid - 64;
            const int r = j / 3;
            const int c = An + (j - r * 3);
            EgL[r * AP + c] = 1.f;
            EcL[r * AP + c] = 1.f;
        }
        float whv = 0.f;
        if (tid < AP) { whv = (tid < An) ? Wh[tid] : 0.f; whL[tid] = whv; }
        if (tid < 64) {    // wave 0 computes Swh
            float sv = whv;
            #pragma unroll
            for (int o = 32; o; o >>= 1) sv += __shfl_xor(sv, o, 64);
            if (tid == 0) swhL = sv;
        }
    }
    __syncthreads();

    const float swh = swhL;

    // ---- z phase: 784 z_t + 16 z_ext ----
    for (int idx = tid; idx < TT * Kn + TT; idx += 256) {
        if (idx < TT * Kn) {
            const int tt = idx / Kn;
            const int k  = idx - tt * Kn;
            const float4* eg4 = (const float4*)&EgL[tt * AP];
            const float4* ev4 = (const float4*)&EvL[k * AP];
            const float4* wh4 = (const float4*)whL;
            float acc = 0.f;
            #pragma unroll
            for (int j = 0; j < 13; ++j) {
                const float4 g = eg4[j], v = ev4[j], w = wh4[j];
                acc += w.x * __builtin_amdgcn_rcpf(g.x * v.x + 1.f);
                acc += w.y * __builtin_amdgcn_rcpf(g.y * v.y + 1.f);
                acc += w.z * __builtin_amdgcn_rcpf(g.z * v.z + 1.f);
                acc += w.w * __builtin_amdgcn_rcpf(g.w * v.w + 1.f);
            }
            zl[tt][k] = swh - 2.f * acc;
        } else {
            const int tt = idx - TT * Kn;
            const float4* ec4 = (const float4*)&EcL[tt * AP];
            const float4* wh4 = (const float4*)whL;
            float acc = 0.f;
            #pragma unroll
            for (int j = 0; j < 13; ++j) {
                const float4 c = ec4[j], w = wh4[j];
                acc += w.x * __builtin_amdgcn_rcpf(c.x + 1.f);
                acc += w.y * __builtin_amdgcn_rcpf(c.y + 1.f);
                acc += w.z * __builtin_amdgcn_rcpf(c.z + 1.f);
                acc += w.w * __builtin_amdgcn_rcpf(c.w + 1.f);
            }
            zl[tt][Kn] = swh - 2.f * acc;
        }
    }
    __syncthreads();

    // ---- softmax: wave w handles rows 4w..4w+3 ----
    {
        const int w    = tid >> 6;
        const int lane = tid & 63;
        #pragma unroll
        for (int rr = 0; rr < 4; ++rr) {
            const int row = w * 4 + rr;
            float v = (lane < Kn) ? zl[row][lane] : -1e30f;
            float m = v;
            #pragma unroll
            for (int o = 32; o; o >>= 1) m = fmaxf(m, __shfl_xor(m, o, 64));
            float e = (lane < Kn) ? __expf(v - m) : 0.f;
            float s = e;
            #pragma unroll
            for (int o = 32; o; o >>= 1) s += __shfl_xor(s, o, 64);
            const float ze  = zl[row][Kn];
            const float m2  = fmaxf(m, ze);
            const float eze = __expf(ze - m2);
            const float denom = s * __expf(m - m2) + eze;
            const float beta  = eze * __builtin_amdgcn_rcpf(denom);
            const float a = e * __builtin_amdgcn_rcpf(s);
            if (lane < AP) al[row][lane] = a;   // lanes 49..51 write 0 (e=0)
            if (lane < Kn)
                out[OUT_ALPHA + ((size_t)(b * Tn + t0 + row)) * Kn + lane] = a;
            if (lane == 0) {
                bl[row] = beta;
                out[OUT_BETA + (b * Tn + t0 + row)] = beta;
            }
        }
    }
    __syncthreads();

    // ---- c_t + c_hat: thread owns float2 h-slice (h = 2*tid) for all 16 rows
    {
        const float2* vb2 = (const float2*)(V + (size_t)b * Kn * Hn);
        float2 acc2[TT];
        #pragma unroll
        for (int r = 0; r < TT; ++r) { acc2[r].x = 0.f; acc2[r].y = 0.f; }

        for (int j = 0; j < 13; ++j) {
            const int k0 = j * 4;
            float2 vv[4];
            #pragma unroll
            for (int u = 0; u < 4; ++u) {
                int kk = k0 + u; kk = (kk > Kn - 1) ? (Kn - 1) : kk;  // al pad=0 masks
                vv[u] = vb2[(size_t)kk * (Hn / 2) + tid];
            }
            #pragma unroll
            for (int r = 0; r < TT; ++r) {
                const float4 a4 = *(const float4*)&al[r][k0];   // broadcast b128
                acc2[r].x += a4.x * vv[0].x + a4.y * vv[1].x + a4.z * vv[2].x + a4.w * vv[3].x;
                acc2[r].y += a4.x * vv[0].y + a4.y * vv[1].y + a4.z * vv[2].y + a4.w * vv[3].y;
            }
        }

        #pragma unroll
        for (int r = 0; r < TT; ++r) {
            const float beta = bl[r];
            const float omb  = 1.f - beta;
            const size_t row = (size_t)(b * Tn + t0 + r) * Hn;
            const float2 sv = *(const float2*)(s_t + row + 2 * tid);
            float2 o;
            o.x = beta * sv.x + omb * acc2[r].x;
            o.y = beta * sv.y + omb * acc2[r].y;
            *(float2*)(out + row + 2 * tid) = o;
        }
    }
}

extern "C" void kernel_launch(void* const* d_in, const int* in_sizes, int n_in,
                              void* d_out, int out_size, void* d_ws, size_t ws_size,
                              hipStream_t stream)
{
    const float* V   = (const float*)d_in[0];
    const float* h_t = (const float*)d_in[1];
    const float* s_t = (const float*)d_in[2];
    const float* Wv  = (const float*)d_in[3];
    const float* Wg  = (const float*)d_in[4];
    const float* Ws  = (const float*)d_in[5];
    const float* Wh  = (const float*)d_in[6];
    float* out = (float*)d_out;
    float* ws  = (float*)d_ws;   // needs ~9.1 MB

    prep_w<<<48, 256, 0, stream>>>(Wv, Wg, Ws, ws);
    dim3 g1(Bn, 3);
    gemm3_mfma<<<g1, 256, 0, stream>>>(V, h_t, s_t, ws);
    fused_kernel<<<Bn * 4, 256, 0, stream>>>(V, s_t, Wh, ws, out);
}